// Round 2
// baseline (187.113 us; speedup 1.0000x reference)
//
#include <hip/hip_runtime.h>
#include <hip/hip_bf16.h>

typedef unsigned short u16;
typedef __bf16 bf16x8 __attribute__((ext_vector_type(8)));
typedef float f32x4 __attribute__((ext_vector_type(4)));

#define NB 16   // batch
#define NK 32   // K slices
#define ND 256  // D
#define NL 256  // L1 == L2

__device__ __forceinline__ u16 f2bf(float f) {
    __hip_bfloat16 h = __float2bfloat16(f);
    return __builtin_bit_cast(u16, h);
}

// ---------------- fused prep: cvt x1/x2/W to bf16 + lin1/lin2 dots ----------------
// blocks 0..1023    : cvt x1  (float4 per thread)
// blocks 1024..2047 : cvt x2
// blocks 2048..4095 : cvt W   (straight, coalesced — no transpose needed anymore)
// blocks 4096..4607 : lin1[b,k,l] = x1[b,l,:].V1[k] + b[k]; lin2[b,k,m] = x2[b,m,:].V2[k]
__global__ void prep_kernel(const float* __restrict__ x1, const float* __restrict__ x2,
                            const float* __restrict__ W, const float* __restrict__ V,
                            const float* __restrict__ bb,
                            u16* __restrict__ x1bf, u16* __restrict__ x2bf, u16* __restrict__ Wbf,
                            float* __restrict__ lin1, float* __restrict__ lin2) {
    int bid = blockIdx.x;
    int tid = threadIdx.x;
    if (bid < 4096) {
        const float* src; u16* dst; long i;
        if (bid < 1024)      { src = x1; dst = x1bf; i = (long)bid * 256 + tid; }
        else if (bid < 2048) { src = x2; dst = x2bf; i = (long)(bid - 1024) * 256 + tid; }
        else                 { src = W;  dst = Wbf;  i = (long)(bid - 2048) * 256 + tid; }
        float4 v = ((const float4*)src)[i];
        ushort4 o;
        o.x = f2bf(v.x); o.y = f2bf(v.y); o.z = f2bf(v.z); o.w = f2bf(v.w);
        ((ushort4*)dst)[i] = o;
    } else {
        int bk = bid - 4096;          // b*NK + k
        int b = bk >> 5, k = bk & 31;
        int t = tid;                  // row index l (or m)
        const float4* r1 = (const float4*)(x1 + ((long)(b * NL + t)) * ND);
        const float4* r2 = (const float4*)(x2 + ((long)(b * NL + t)) * ND);
        const float4* v1 = (const float4*)(V + (long)k * (2 * ND));
        const float4* v2 = v1 + (ND / 4);
        float s1 = 0.f, s2 = 0.f;
#pragma unroll 8
        for (int i = 0; i < ND / 4; ++i) {
            float4 a = r1[i], w = v1[i];
            s1 += a.x * w.x + a.y * w.y + a.z * w.z + a.w * w.w;
            float4 c = r2[i], u = v2[i];
            s2 += c.x * u.x + c.y * u.y + c.z * u.z + c.w * u.w;
        }
        lin1[(long)bk * NL + t] = s1 + bb[k];
        lin2[(long)bk * NL + t] = s2;
    }
}

// ---------------- main fused kernel ----------------
// grid: 512 blocks = (b,k); 512 threads = 8 waves (4 wave-rows x 2 wave-cols)
// phase A': U[d][m] = sum_e W[k][d][e] * x2[b][m][e]   (all frags direct from global, row-major)
//           -> write U^T[m][d] bf16 into LDS (XOR-swizzled, packed 8B writes)
// phase B : O[l][m] = sum_d x1[b][l][d] * U^T[m][d]    (A from global, B from LDS)
// ONE barrier per block. No W transpose anywhere.
__launch_bounds__(512, 2)
__global__ void ntn_main(const u16* __restrict__ x1bf, const u16* __restrict__ x2bf,
                         const u16* __restrict__ Wbf,
                         const float* __restrict__ lin1, const float* __restrict__ lin2,
                         float* __restrict__ out) {
    __shared__ u16 ldsU[256 * 256];   // 128 KiB: U^T[m][d], rows 512 B, swizzle byte^=((m&7)<<4)

    int bid = blockIdx.x;
    int sw = ((bid & 7) << 6) | (bid >> 3);   // XCD-contiguous chunks (512 % 8 == 0, bijective)
    int k = sw >> 4;
    int b = sw & 15;

    int tid  = threadIdx.x;
    int lane = tid & 63;
    int wid  = tid >> 6;
    int wr = wid >> 1;             // wave row 0..3 (64 M-rows each)
    int wc = wid & 1;              // wave col 0..1 (128 N-cols each)
    int lrow = lane & 15;
    int lk8  = (lane >> 4) << 3;   // k-dim element offset 0/8/16/24
    int j4   = (lane >> 4) << 2;   // C/D row offset 0/4/8/12

    f32x4 acc[4][8];
    const f32x4 fz = {0.f, 0.f, 0.f, 0.f};
#pragma unroll
    for (int i = 0; i < 4; ++i)
#pragma unroll
        for (int j = 0; j < 8; ++j) acc[i][j] = fz;

    // ================= phase A': U = W[k] @ x2[b]^T  (M=d, N=m, K=e) =================
    {
        const u16* wp  = Wbf  + ((long)k << 16);
        const u16* x2p = x2bf + ((long)b << 16);
#pragma unroll
        for (int et = 0; et < 8; ++et) {
            int e = (et << 5) + lk8;
            bf16x8 af[4], bfr[8];
#pragma unroll
            for (int lt = 0; lt < 4; ++lt)
                af[lt] = *(const bf16x8*)(wp + (((wr << 6) + (lt << 4) + lrow) << 8) + e);
#pragma unroll
            for (int nt = 0; nt < 8; ++nt)
                bfr[nt] = *(const bf16x8*)(x2p + (((wc << 7) + (nt << 4) + lrow) << 8) + e);
#pragma unroll
            for (int nt = 0; nt < 8; ++nt)
#pragma unroll
                for (int lt = 0; lt < 4; ++lt)
                    acc[lt][nt] = __builtin_amdgcn_mfma_f32_16x16x32_bf16(af[lt], bfr[nt], acc[lt][nt], 0, 0, 0);
        }
    }

    // ---- write U^T[m][d] to LDS, swizzled, 4 bf16 packed per 8B write
#pragma unroll
    for (int lt = 0; lt < 4; ++lt) {
        int db = (wr << 6) + (lt << 4) + j4;   // d of acc[..][0], consecutive j = consecutive d
#pragma unroll
        for (int nt = 0; nt < 8; ++nt) {
            int m = (wc << 7) + (nt << 4) + lrow;
            ushort4 pk;
            pk.x = f2bf(acc[lt][nt][0]);
            pk.y = f2bf(acc[lt][nt][1]);
            pk.z = f2bf(acc[lt][nt][2]);
            pk.w = f2bf(acc[lt][nt][3]);
            *(ushort4*)((char*)ldsU + (m << 9) + ((db << 1) ^ ((m & 7) << 4))) = pk;
        }
    }
    __syncthreads();

#pragma unroll
    for (int i = 0; i < 4; ++i)
#pragma unroll
        for (int j = 0; j < 8; ++j) acc[i][j] = fz;

    // ================= phase B: O = x1[b] @ U  (M=l, N=m, K=d) =================
    {
        const u16* x1p = x1bf + ((long)b << 16);
#pragma unroll
        for (int dt = 0; dt < 8; ++dt) {
            int d = (dt << 5) + lk8;
            bf16x8 af[4], bfr[8];
#pragma unroll
            for (int lt = 0; lt < 4; ++lt)
                af[lt] = *(const bf16x8*)(x1p + (((wr << 6) + (lt << 4) + lrow) << 8) + d);
#pragma unroll
            for (int nt = 0; nt < 8; ++nt) {
                int m = (wc << 7) + (nt << 4) + lrow;
                bfr[nt] = *(const bf16x8*)((const char*)ldsU + (m << 9) + ((d << 1) ^ ((m & 7) << 4)));
            }
#pragma unroll
            for (int nt = 0; nt < 8; ++nt)
#pragma unroll
                for (int lt = 0; lt < 4; ++lt)
                    acc[lt][nt] = __builtin_amdgcn_mfma_f32_16x16x32_bf16(af[lt], bfr[nt], acc[lt][nt], 0, 0, 0);
        }
    }

    // ================= epilogue: + lin1 + lin2 (+b folded), relu, nontemporal f32 store ===
    {
        const float* l1p = lin1 + (((long)(b * NK + k)) << 8);
        const float* l2p = lin2 + (((long)(b * NK + k)) << 8);
        float colb[8];
#pragma unroll
        for (int nt = 0; nt < 8; ++nt) colb[nt] = l2p[(wc << 7) + (nt << 4) + lrow];
        float* outp = out + (((long)(b * NK + k)) << 16);
#pragma unroll
        for (int lt = 0; lt < 4; ++lt) {
#pragma unroll
            for (int j = 0; j < 4; ++j) {
                int l = (wr << 6) + (lt << 4) + j4 + j;
                float rb = l1p[l];
#pragma unroll
                for (int nt = 0; nt < 8; ++nt) {
                    float v = acc[lt][nt][j] + rb + colb[nt];
                    v = v > 0.f ? v : 0.f;
                    __builtin_nontemporal_store(v, outp + ((long)l << 8) + (wc << 7) + (nt << 4) + lrow);
                }
            }
        }
    }
}

extern "C" void kernel_launch(void* const* d_in, const int* in_sizes, int n_in,
                              void* d_out, int out_size, void* d_ws, size_t ws_size,
                              hipStream_t stream) {
    const float* x1 = (const float*)d_in[0];
    const float* x2 = (const float*)d_in[1];
    const float* W  = (const float*)d_in[2];
    const float* V  = (const float*)d_in[3];
    const float* bb = (const float*)d_in[4];
    float* out = (float*)d_out;

    char* ws = (char*)d_ws;
    u16*   x1bf = (u16*)(ws);                               // 2 MiB
    u16*   x2bf = (u16*)(ws + (2l << 20));                  // 2 MiB
    u16*   Wbf  = (u16*)(ws + (4l << 20));                  // 4 MiB
    float* lin1 = (float*)(ws + (8l << 20));                // 512 KiB
    float* lin2 = (float*)(ws + (8l << 20) + (512l << 10)); // 512 KiB

    hipLaunchKernelGGL(prep_kernel, dim3(4608), dim3(256), 0, stream,
                       x1, x2, W, V, bb, x1bf, x2bf, Wbf, lin1, lin2);
    hipLaunchKernelGGL(ntn_main, dim3(NB * NK), dim3(512), 0, stream,
                       x1bf, x2bf, Wbf, lin1, lin2, out);
}

// Round 3
// 166.184 us; speedup vs baseline: 1.1259x; 1.1259x over previous
//
#include <hip/hip_runtime.h>
#include <hip/hip_bf16.h>

typedef unsigned short u16;
typedef unsigned short ushort8v __attribute__((ext_vector_type(8)));
typedef __bf16 bf16x8 __attribute__((ext_vector_type(8)));
typedef float f32x4 __attribute__((ext_vector_type(4)));

#define NB 16   // batch
#define NK 32   // K slices
#define ND 256  // D
#define NL 256  // L1 == L2

__device__ __forceinline__ u16 f2bf(float f) {
    __hip_bfloat16 h = __float2bfloat16(f);
    return __builtin_bit_cast(u16, h);
}

__device__ __forceinline__ bf16x8 pack8(float4 a, float4 b) {
    ushort8v u;
    u[0] = f2bf(a.x); u[1] = f2bf(a.y); u[2] = f2bf(a.z); u[3] = f2bf(a.w);
    u[4] = f2bf(b.x); u[5] = f2bf(b.y); u[6] = f2bf(b.z); u[7] = f2bf(b.w);
    return __builtin_bit_cast(bf16x8, u);
}

// ---------------- fused prep ----------------
// blocks 0..15      : lin1/lin2 via MFMA (reads raw f32 x1/x2/V — no dependency on cvt blocks)
// blocks 16..1039   : cvt x1   (float4 per thread)
// blocks 1040..2063 : cvt x2
// blocks 2064..4111 : cvt W    (straight, coalesced)
__global__ void prep_kernel(const float* __restrict__ x1, const float* __restrict__ x2,
                            const float* __restrict__ W, const float* __restrict__ V,
                            const float* __restrict__ bb,
                            u16* __restrict__ x1bf, u16* __restrict__ x2bf, u16* __restrict__ Wbf,
                            float* __restrict__ lin1, float* __restrict__ lin2) {
    int bid = blockIdx.x;
    int tid = threadIdx.x;
    if (bid >= 16) {
        int cb = bid - 16;
        const float* src; u16* dst; long i;
        if (cb < 1024)      { src = x1; dst = x1bf; i = (long)cb * 256 + tid; }
        else if (cb < 2048) { src = x2; dst = x2bf; i = (long)(cb - 1024) * 256 + tid; }
        else                { src = W;  dst = Wbf;  i = (long)(cb - 2048) * 256 + tid; }
        float4 v = ((const float4*)src)[i];
        ushort4 o;
        o.x = f2bf(v.x); o.y = f2bf(v.y); o.z = f2bf(v.z); o.w = f2bf(v.w);
        ((ushort4*)dst)[i] = o;
        return;
    }
    // ---- lin blocks: lin1[b,k,l] = x1[b,l,:].V1[k] + bb[k]; lin2[b,k,m] = x2[b,m,:].V2[k]
    int b    = bid;
    int lane = tid & 63;
    int wv   = tid >> 6;            // 4 waves, 64 l-rows each
    int lrow = lane & 15;
    int lk8  = (lane >> 4) << 3;
    int j4   = (lane >> 4) << 2;
    int lbase = wv << 6;

    const f32x4 fz = {0.f, 0.f, 0.f, 0.f};
#pragma unroll
    for (int pass = 0; pass < 2; ++pass) {
        const float* xp = (pass ? x2 : x1) + ((long)b << 16);
        const float* vp = V + (pass ? ND : 0);
        f32x4 acc[4][2];
#pragma unroll
        for (int i = 0; i < 4; ++i) { acc[i][0] = fz; acc[i][1] = fz; }
#pragma unroll
        for (int dt = 0; dt < 8; ++dt) {
            int d = (dt << 5) + lk8;
            bf16x8 af[4], bf[2];
#pragma unroll
            for (int lt = 0; lt < 4; ++lt) {
                const float4* s = (const float4*)(xp + ((long)((lbase + (lt << 4) + lrow)) << 8) + d);
                af[lt] = pack8(s[0], s[1]);
            }
#pragma unroll
            for (int nt = 0; nt < 2; ++nt) {
                const float4* s = (const float4*)(vp + (long)((nt << 4) + lrow) * (2 * ND) + d);
                bf[nt] = pack8(s[0], s[1]);
            }
#pragma unroll
            for (int nt = 0; nt < 2; ++nt)
#pragma unroll
                for (int lt = 0; lt < 4; ++lt)
                    acc[lt][nt] = __builtin_amdgcn_mfma_f32_16x16x32_bf16(af[lt], bf[nt], acc[lt][nt], 0, 0, 0);
        }
        float* dst = (pass ? lin2 : lin1) + ((long)b << 13);
#pragma unroll
        for (int nt = 0; nt < 2; ++nt) {
            int kk = (nt << 4) + lrow;
            float add = pass ? 0.f : bb[kk];
#pragma unroll
            for (int lt = 0; lt < 4; ++lt) {
                float4 v;
                v.x = acc[lt][nt][0] + add; v.y = acc[lt][nt][1] + add;
                v.z = acc[lt][nt][2] + add; v.w = acc[lt][nt][3] + add;
                *(float4*)(dst + ((long)kk << 8) + lbase + (lt << 4) + j4) = v;
            }
        }
    }
}

// ---------------- main fused kernel ----------------
// grid: 512 blocks = (b,k); 1024 threads = 16 waves (4 wave-rows x 4 wave-cols), tile 64x64
// phase A': U[d][m] = sum_e W[k][d][e] * x2[b][m][e]   (frags direct from global, row-major)
//           -> U^T[m][d] bf16 into LDS (XOR-swizzled, packed 8B writes)
// phase B : O[l][m] = sum_d x1[b][l][d] * U^T[m][d]    (A from global, B from LDS)
// ONE barrier per block.
__launch_bounds__(1024, 4)
__global__ void ntn_main(const u16* __restrict__ x1bf, const u16* __restrict__ x2bf,
                         const u16* __restrict__ Wbf,
                         const float* __restrict__ lin1, const float* __restrict__ lin2,
                         float* __restrict__ out) {
    __shared__ u16 ldsU[256 * 256];   // 128 KiB: U^T[m][d], rows 512 B, swizzle byte^=((m&7)<<4)

    int bid = blockIdx.x;
    int sw = ((bid & 7) << 6) | (bid >> 3);   // XCD-contiguous chunks (512 % 8 == 0, bijective)
    int k = sw >> 4;
    int b = sw & 15;

    int tid  = threadIdx.x;
    int lane = tid & 63;
    int wid  = tid >> 6;
    int wr = wid >> 2;             // wave row 0..3 (64 M-rows each)
    int wc = wid & 3;              // wave col 0..3 (64 N-cols each)
    int lrow = lane & 15;
    int lk8  = (lane >> 4) << 3;   // k-dim element offset 0/8/16/24
    int j4   = (lane >> 4) << 2;   // C/D row offset 0/4/8/12

    f32x4 acc[4][4];
    const f32x4 fz = {0.f, 0.f, 0.f, 0.f};
#pragma unroll
    for (int i = 0; i < 4; ++i)
#pragma unroll
        for (int j = 0; j < 4; ++j) acc[i][j] = fz;

    // ================= phase A': U = W[k] @ x2[b]^T  (M=d, N=m, K=e) =================
    {
        const u16* wp  = Wbf  + ((long)k << 16);
        const u16* x2p = x2bf + ((long)b << 16);
#pragma unroll
        for (int et = 0; et < 8; ++et) {
            int e = (et << 5) + lk8;
            bf16x8 af[4], bfr[4];
#pragma unroll
            for (int lt = 0; lt < 4; ++lt)
                af[lt] = *(const bf16x8*)(wp + (((wr << 6) + (lt << 4) + lrow) << 8) + e);
#pragma unroll
            for (int nt = 0; nt < 4; ++nt)
                bfr[nt] = *(const bf16x8*)(x2p + (((wc << 6) + (nt << 4) + lrow) << 8) + e);
#pragma unroll
            for (int nt = 0; nt < 4; ++nt)
#pragma unroll
                for (int lt = 0; lt < 4; ++lt)
                    acc[lt][nt] = __builtin_amdgcn_mfma_f32_16x16x32_bf16(af[lt], bfr[nt], acc[lt][nt], 0, 0, 0);
        }
    }

    // ---- write U^T[m][d] to LDS, swizzled, 4 bf16 packed per 8B write
#pragma unroll
    for (int lt = 0; lt < 4; ++lt) {
        int db = (wr << 6) + (lt << 4) + j4;   // d of acc[..][0], consecutive j = consecutive d
#pragma unroll
        for (int nt = 0; nt < 4; ++nt) {
            int m = (wc << 6) + (nt << 4) + lrow;
            ushort4 pk;
            pk.x = f2bf(acc[lt][nt][0]);
            pk.y = f2bf(acc[lt][nt][1]);
            pk.z = f2bf(acc[lt][nt][2]);
            pk.w = f2bf(acc[lt][nt][3]);
            *(ushort4*)((char*)ldsU + (m << 9) + ((db << 1) ^ ((m & 7) << 4))) = pk;
        }
    }
    __syncthreads();

#pragma unroll
    for (int i = 0; i < 4; ++i)
#pragma unroll
        for (int j = 0; j < 4; ++j) acc[i][j] = fz;

    // ================= phase B: O = x1[b] @ U  (M=l, N=m, K=d) =================
    {
        const u16* x1p = x1bf + ((long)b << 16);
#pragma unroll
        for (int dt = 0; dt < 8; ++dt) {
            int d = (dt << 5) + lk8;
            bf16x8 af[4], bfr[4];
#pragma unroll
            for (int lt = 0; lt < 4; ++lt)
                af[lt] = *(const bf16x8*)(x1p + (((wr << 6) + (lt << 4) + lrow) << 8) + d);
#pragma unroll
            for (int nt = 0; nt < 4; ++nt) {
                int m = (wc << 6) + (nt << 4) + lrow;
                bfr[nt] = *(const bf16x8*)((const char*)ldsU + (m << 9) + ((d << 1) ^ ((m & 7) << 4)));
            }
#pragma unroll
            for (int nt = 0; nt < 4; ++nt)
#pragma unroll
                for (int lt = 0; lt < 4; ++lt)
                    acc[lt][nt] = __builtin_amdgcn_mfma_f32_16x16x32_bf16(af[lt], bfr[nt], acc[lt][nt], 0, 0, 0);
        }
    }

    // ================= epilogue: + lin1 + lin2 (+b folded), relu, nontemporal f32 store ===
    {
        const float* l1p = lin1 + (((long)(b * NK + k)) << 8);
        const float* l2p = lin2 + (((long)(b * NK + k)) << 8);
        float colb[4];
#pragma unroll
        for (int nt = 0; nt < 4; ++nt) colb[nt] = l2p[(wc << 6) + (nt << 4) + lrow];
        float* outp = out + (((long)(b * NK + k)) << 16);
#pragma unroll
        for (int lt = 0; lt < 4; ++lt) {
#pragma unroll
            for (int j = 0; j < 4; ++j) {
                int l = (wr << 6) + (lt << 4) + j4 + j;
                float rb = l1p[l];
#pragma unroll
                for (int nt = 0; nt < 4; ++nt) {
                    float v = acc[lt][nt][j] + rb + colb[nt];
                    v = v > 0.f ? v : 0.f;
                    __builtin_nontemporal_store(v, outp + ((long)l << 8) + (wc << 6) + (nt << 4) + lrow);
                }
            }
        }
    }
}

extern "C" void kernel_launch(void* const* d_in, const int* in_sizes, int n_in,
                              void* d_out, int out_size, void* d_ws, size_t ws_size,
                              hipStream_t stream) {
    const float* x1 = (const float*)d_in[0];
    const float* x2 = (const float*)d_in[1];
    const float* W  = (const float*)d_in[2];
    const float* V  = (const float*)d_in[3];
    const float* bb = (const float*)d_in[4];
    float* out = (float*)d_out;

    char* ws = (char*)d_ws;
    u16*   x1bf = (u16*)(ws);                               // 2 MiB
    u16*   x2bf = (u16*)(ws + (2l << 20));                  // 2 MiB
    u16*   Wbf  = (u16*)(ws + (4l << 20));                  // 4 MiB
    float* lin1 = (float*)(ws + (8l << 20));                // 512 KiB
    float* lin2 = (float*)(ws + (8l << 20) + (512l << 10)); // 512 KiB

    hipLaunchKernelGGL(prep_kernel, dim3(4112), dim3(256), 0, stream,
                       x1, x2, W, V, bb, x1bf, x2bf, Wbf, lin1, lin2);
    hipLaunchKernelGGL(ntn_main, dim3(NB * NK), dim3(1024), 0, stream,
                       x1bf, x2bf, Wbf, lin1, lin2, out);
}

// Round 4
// 130.549 us; speedup vs baseline: 1.4333x; 1.2730x over previous
//
#include <hip/hip_runtime.h>
#include <hip/hip_bf16.h>

typedef unsigned short u16;
typedef unsigned short ushort8v __attribute__((ext_vector_type(8)));
typedef __bf16 bf16x8 __attribute__((ext_vector_type(8)));
typedef float f32x4 __attribute__((ext_vector_type(4)));

#define NB 16   // batch
#define NK 32   // K slices
#define ND 256  // D
#define NL 256  // L1 == L2

__device__ __forceinline__ u16 f2bf(float f) {
    __hip_bfloat16 h = __float2bfloat16(f);
    return __builtin_bit_cast(u16, h);
}

__device__ __forceinline__ bf16x8 pack8(float4 a, float4 b) {
    ushort8v u;
    u[0] = f2bf(a.x); u[1] = f2bf(a.y); u[2] = f2bf(a.z); u[3] = f2bf(a.w);
    u[4] = f2bf(b.x); u[5] = f2bf(b.y); u[6] = f2bf(b.z); u[7] = f2bf(b.w);
    return __builtin_bit_cast(bf16x8, u);
}

// Fragment-order layout for a 256x256 matrix X[r][c] (c = contraction dim):
//   buf[((rt*8 + ct)*64 + lane)*8 + (c&7)], rt=r>>4, ct=c>>5,
//   lane = (r&15) | (((c>>3)&3)<<4)
// => a wave's 16x16x32 MFMA fragment (row-tile rt, c-tile ct) is 1 KiB contiguous,
//    lane i reads bytes [i*16, i*16+16) — perfectly coalesced global_load_dwordx4.

// ---------------- fused prep ----------------
// blocks 0..1023    : x1 f32 -> frag-order bf16
// blocks 1024..2047 : x2  "
// blocks 2048..4095 : W   "
// blocks 4096..4127 : lin1/lin2 via MFMA (reads raw f32 — independent of cvt blocks)
__global__ void prep_kernel(const float* __restrict__ x1, const float* __restrict__ x2,
                            const float* __restrict__ W, const float* __restrict__ V,
                            const float* __restrict__ bb,
                            u16* __restrict__ x1f, u16* __restrict__ x2f, u16* __restrict__ Wf,
                            float* __restrict__ lin1, float* __restrict__ lin2) {
    int bid = blockIdx.x;
    int tid = threadIdx.x;
    if (bid < 4096) {
        const float* src; u16* dst; long f4;
        if (bid < 1024)      { src = x1; dst = x1f; f4 = (long)bid * 256 + tid; }
        else if (bid < 2048) { src = x2; dst = x2f; f4 = (long)(bid - 1024) * 256 + tid; }
        else                 { src = W;  dst = Wf;  f4 = (long)(bid - 2048) * 256 + tid; }
        long idx = f4 << 2;                  // f32 element index within matrix region
        int mat = (int)(idx >> 16);          // which 256x256 slab (k for W, b for x1/x2)
        int r = (int)((idx >> 8) & 255);
        int c = (int)(idx & 255);
        float4 v = ((const float4*)src)[f4];
        ushort4 o;
        o.x = f2bf(v.x); o.y = f2bf(v.y); o.z = f2bf(v.z); o.w = f2bf(v.w);
        int rt = r >> 4, ct = c >> 5;
        int lane = (r & 15) | (((c >> 3) & 3) << 4);
        long off = ((long)mat << 16) + (((rt << 3) + ct) << 9) + (lane << 3) + (c & 7);
        *(ushort4*)(dst + off) = o;
        return;
    }
    // ---- lin blocks (32): bid2 = (b, pass)
    int bid2 = bid - 4096;
    int b = bid2 >> 1, pass = bid2 & 1;
    int lane = tid & 63;
    int wv   = tid >> 6;            // 4 waves, 64 l-rows each
    int lrow = lane & 15;
    int lk8  = (lane >> 4) << 3;
    int j4   = (lane >> 4) << 2;
    int lbase = wv << 6;

    const f32x4 fz = {0.f, 0.f, 0.f, 0.f};
    const float* xp = (pass ? x2 : x1) + ((long)b << 16);
    const float* vp = V + (pass ? ND : 0);
    f32x4 acc[4][2];
#pragma unroll
    for (int i = 0; i < 4; ++i) { acc[i][0] = fz; acc[i][1] = fz; }
#pragma unroll
    for (int dt = 0; dt < 8; ++dt) {
        int d = (dt << 5) + lk8;
        bf16x8 af[4], bf[2];
#pragma unroll
        for (int lt = 0; lt < 4; ++lt) {
            const float4* s = (const float4*)(xp + ((long)((lbase + (lt << 4) + lrow)) << 8) + d);
            af[lt] = pack8(s[0], s[1]);
        }
#pragma unroll
        for (int nt = 0; nt < 2; ++nt) {
            const float4* s = (const float4*)(vp + (long)((nt << 4) + lrow) * (2 * ND) + d);
            bf[nt] = pack8(s[0], s[1]);
        }
#pragma unroll
        for (int nt = 0; nt < 2; ++nt)
#pragma unroll
            for (int lt = 0; lt < 4; ++lt)
                acc[lt][nt] = __builtin_amdgcn_mfma_f32_16x16x32_bf16(af[lt], bf[nt], acc[lt][nt], 0, 0, 0);
    }
    float* dst = (pass ? lin2 : lin1) + ((long)b << 13);
#pragma unroll
    for (int nt = 0; nt < 2; ++nt) {
        int kk = (nt << 4) + lrow;
        float add = pass ? 0.f : bb[kk];
#pragma unroll
        for (int lt = 0; lt < 4; ++lt) {
            float4 v;
            v.x = acc[lt][nt][0] + add; v.y = acc[lt][nt][1] + add;
            v.z = acc[lt][nt][2] + add; v.w = acc[lt][nt][3] + add;
            *(float4*)(dst + ((long)kk << 8) + lbase + (lt << 4) + j4) = v;
        }
    }
}

// ---------------- main fused kernel ----------------
// grid: 1024 blocks = (k, b, mq); 512 threads = 8 waves (4 wave-rows x 2 wave-cols)
// phase A: U^T[m'][d] (m' = this block's 128-col half) = sum_e W[k][d][e]*x2[b][m][e]
//          A-frag = W (M=d, 4 wave-rows x 64), B-frag = x2 (N=m, 2 wave-cols x 64)
//          all frags coalesced 1KiB loads from frag-order global. Result -> LDS (64 KiB).
// phase B: O[l][m'] = sum_d x1[b][l][d] * U^T[m'][d]
//          A-frag = x1 from frag-order global, B-frag = U^T from LDS (XOR-swizzled).
// ONE barrier per block; 2 blocks/CU (64 KiB LDS), 16 waves/CU.
__launch_bounds__(512, 4)
__global__ void ntn_main(const u16* __restrict__ x1f, const u16* __restrict__ x2f,
                         const u16* __restrict__ Wf,
                         const float* __restrict__ lin1, const float* __restrict__ lin2,
                         float* __restrict__ out) {
    __shared__ u16 ldsU[128 * 256];   // 64 KiB: U^T[m'][d], rows 512 B, swizzle byte^=((m&7)<<4)

    int bid = blockIdx.x;
    int sw = ((bid & 7) << 7) | (bid >> 3);   // XCD-contiguous chunks (1024%8==0, bijective)
    int k  = sw >> 5;
    int b  = (sw >> 1) & 15;
    int mq = sw & 1;

    int tid  = threadIdx.x;
    int lane = tid & 63;
    int wid  = tid >> 6;
    int wr = wid >> 1;             // wave row 0..3
    int wc = wid & 1;              // wave col 0..1
    int lrow = lane & 15;
    int lk8  = (lane >> 4) << 3;
    int j4   = (lane >> 4) << 2;

    f32x4 acc[4][4];
    const f32x4 fz = {0.f, 0.f, 0.f, 0.f};
#pragma unroll
    for (int i = 0; i < 4; ++i)
#pragma unroll
        for (int j = 0; j < 4; ++j) acc[i][j] = fz;

    // ================= phase A: U^T = (W[k] @ x2[b]^T)^T, frag loads coalesced ========
    {
        const u16* wp  = Wf  + ((long)k << 16);                      // 16 d-tiles x 8 e-tiles
        const u16* x2p = x2f + ((long)b << 16) + ((long)mq << 15);   // 8 m-tiles x 8 e-tiles
#pragma unroll
        for (int et = 0; et < 8; ++et) {
            bf16x8 af[4], bfr[4];
#pragma unroll
            for (int lt = 0; lt < 4; ++lt)
                af[lt] = *(const bf16x8*)(wp + (((((wr << 2) + lt) << 3) + et) << 9) + (lane << 3));
#pragma unroll
            for (int nt = 0; nt < 4; ++nt)
                bfr[nt] = *(const bf16x8*)(x2p + (((((wc << 2) + nt) << 3) + et) << 9) + (lane << 3));
#pragma unroll
            for (int nt = 0; nt < 4; ++nt)
#pragma unroll
                for (int lt = 0; lt < 4; ++lt)
                    acc[lt][nt] = __builtin_amdgcn_mfma_f32_16x16x32_bf16(af[lt], bfr[nt], acc[lt][nt], 0, 0, 0);
        }
    }

    // ---- write U^T[m'][d] to LDS, swizzled, 4 bf16 packed per 8B write
#pragma unroll
    for (int lt = 0; lt < 4; ++lt) {
        int d0 = (wr << 6) + (lt << 4) + j4;   // consecutive j = consecutive d
#pragma unroll
        for (int nt = 0; nt < 4; ++nt) {
            int m = (wc << 6) + (nt << 4) + lrow;   // local m' 0..127
            ushort4 pk;
            pk.x = f2bf(acc[lt][nt][0]);
            pk.y = f2bf(acc[lt][nt][1]);
            pk.z = f2bf(acc[lt][nt][2]);
            pk.w = f2bf(acc[lt][nt][3]);
            *(ushort4*)((char*)ldsU + (m << 9) + ((d0 << 1) ^ ((m & 7) << 4))) = pk;
        }
    }
    __syncthreads();

#pragma unroll
    for (int i = 0; i < 4; ++i)
#pragma unroll
        for (int j = 0; j < 4; ++j) acc[i][j] = fz;

    // ================= phase B: O = x1[b] @ U^T^T  (M=l, N=m', K=d) =================
    {
        const u16* x1p = x1f + ((long)b << 16);
#pragma unroll
        for (int dt = 0; dt < 8; ++dt) {
            int d = (dt << 5) + lk8;
            bf16x8 af[4], bfr[4];
#pragma unroll
            for (int lt = 0; lt < 4; ++lt)
                af[lt] = *(const bf16x8*)(x1p + (((((wr << 2) + lt) << 3) + dt) << 9) + (lane << 3));
#pragma unroll
            for (int nt = 0; nt < 4; ++nt) {
                int m = (wc << 6) + (nt << 4) + lrow;
                bfr[nt] = *(const bf16x8*)((const char*)ldsU + (m << 9) + ((d << 1) ^ ((m & 7) << 4)));
            }
#pragma unroll
            for (int nt = 0; nt < 4; ++nt)
#pragma unroll
                for (int lt = 0; lt < 4; ++lt)
                    acc[lt][nt] = __builtin_amdgcn_mfma_f32_16x16x32_bf16(af[lt], bfr[nt], acc[lt][nt], 0, 0, 0);
        }
    }

    // ================= epilogue: + lin1 + lin2 (+b folded), relu, nontemporal store ====
    {
        const float* l1p = lin1 + (((long)(b * NK + k)) << 8);
        const float* l2p = lin2 + (((long)(b * NK + k)) << 8);
        int cbase = (mq << 7) + (wc << 6);
        float colb[4];
#pragma unroll
        for (int nt = 0; nt < 4; ++nt) colb[nt] = l2p[cbase + (nt << 4) + lrow];
        float* outp = out + (((long)(b * NK + k)) << 16);
#pragma unroll
        for (int lt = 0; lt < 4; ++lt) {
#pragma unroll
            for (int j = 0; j < 4; ++j) {
                int l = (wr << 6) + (lt << 4) + j4 + j;
                float rb = l1p[l];
#pragma unroll
                for (int nt = 0; nt < 4; ++nt) {
                    float v = acc[lt][nt][j] + rb + colb[nt];
                    v = v > 0.f ? v : 0.f;
                    __builtin_nontemporal_store(v, outp + ((long)l << 8) + cbase + (nt << 4) + lrow);
                }
            }
        }
    }
}

extern "C" void kernel_launch(void* const* d_in, const int* in_sizes, int n_in,
                              void* d_out, int out_size, void* d_ws, size_t ws_size,
                              hipStream_t stream) {
    const float* x1 = (const float*)d_in[0];
    const float* x2 = (const float*)d_in[1];
    const float* W  = (const float*)d_in[2];
    const float* V  = (const float*)d_in[3];
    const float* bb = (const float*)d_in[4];
    float* out = (float*)d_out;

    char* ws = (char*)d_ws;
    u16*   x1f  = (u16*)(ws);                               // 2 MiB
    u16*   x2f  = (u16*)(ws + (2l << 20));                  // 2 MiB
    u16*   Wf   = (u16*)(ws + (4l << 20));                  // 4 MiB
    float* lin1 = (float*)(ws + (8l << 20));                // 512 KiB
    float* lin2 = (float*)(ws + (8l << 20) + (512l << 10)); // 512 KiB

    hipLaunchKernelGGL(prep_kernel, dim3(4128), dim3(256), 0, stream,
                       x1, x2, W, V, bb, x1f, x2f, Wf, lin1, lin2);
    hipLaunchKernelGGL(ntn_main, dim3(1024), dim3(512), 0, stream,
                       x1f, x2f, Wf, lin1, lin2, out);
}

// Round 5
// 111.913 us; speedup vs baseline: 1.6719x; 1.1665x over previous
//
#include <hip/hip_runtime.h>
#include <hip/hip_bf16.h>

typedef unsigned short u16;
typedef unsigned short ushort8v __attribute__((ext_vector_type(8)));
typedef __bf16 bf16x8 __attribute__((ext_vector_type(8)));
typedef float f32x4 __attribute__((ext_vector_type(4)));

#define NB 16   // batch
#define NK 32   // K slices
#define ND 256  // D
#define NL 256  // L1 == L2

__device__ __forceinline__ u16 f2bf(float f) {
    __hip_bfloat16 h = __float2bfloat16(f);
    return __builtin_bit_cast(u16, h);
}

__device__ __forceinline__ bf16x8 pack8(float4 a, float4 b) {
    ushort8v u;
    u[0] = f2bf(a.x); u[1] = f2bf(a.y); u[2] = f2bf(a.z); u[3] = f2bf(a.w);
    u[4] = f2bf(b.x); u[5] = f2bf(b.y); u[6] = f2bf(b.z); u[7] = f2bf(b.w);
    return __builtin_bit_cast(bf16x8, u);
}

// Fragment-order layout for a 256x256 matrix X[r][c] (c = contraction dim):
//   buf[((rt*8 + ct)*64 + lane)*8 + (c&7)], rt=r>>4, ct=c>>5,
//   lane = (r&15) | (((c>>3)&3)<<4)
// => a wave's 16x16x32 MFMA fragment (row-tile rt, c-tile ct) is 1 KiB contiguous,
//    lane i reads bytes [i*16, i*16+16) — perfectly coalesced global_load_dwordx4.

// ---------------- fused prep ----------------
// blocks 0..1023    : x1 f32 -> frag-order bf16
// blocks 1024..2047 : x2  "
// blocks 2048..4095 : W   "
// blocks 4096..4127 : lin1/lin2 via MFMA (reads raw f32 — independent of cvt blocks)
__global__ void prep_kernel(const float* __restrict__ x1, const float* __restrict__ x2,
                            const float* __restrict__ W, const float* __restrict__ V,
                            const float* __restrict__ bb,
                            u16* __restrict__ x1f, u16* __restrict__ x2f, u16* __restrict__ Wf,
                            float* __restrict__ lin1, float* __restrict__ lin2) {
    int bid = blockIdx.x;
    int tid = threadIdx.x;
    if (bid < 4096) {
        const float* src; u16* dst; long f4;
        if (bid < 1024)      { src = x1; dst = x1f; f4 = (long)bid * 256 + tid; }
        else if (bid < 2048) { src = x2; dst = x2f; f4 = (long)(bid - 1024) * 256 + tid; }
        else                 { src = W;  dst = Wf;  f4 = (long)(bid - 2048) * 256 + tid; }
        long idx = f4 << 2;                  // f32 element index within matrix region
        int mat = (int)(idx >> 16);          // which 256x256 slab (k for W, b for x1/x2)
        int r = (int)((idx >> 8) & 255);
        int c = (int)(idx & 255);
        float4 v = ((const float4*)src)[f4];
        ushort4 o;
        o.x = f2bf(v.x); o.y = f2bf(v.y); o.z = f2bf(v.z); o.w = f2bf(v.w);
        int rt = r >> 4, ct = c >> 5;
        int lane = (r & 15) | (((c >> 3) & 3) << 4);
        long off = ((long)mat << 16) + (((rt << 3) + ct) << 9) + (lane << 3) + (c & 7);
        *(ushort4*)(dst + off) = o;
        return;
    }
    // ---- lin blocks (32): bid2 = (b, pass)
    int bid2 = bid - 4096;
    int b = bid2 >> 1, pass = bid2 & 1;
    int lane = tid & 63;
    int wv   = tid >> 6;            // 4 waves, 64 l-rows each
    int lrow = lane & 15;
    int lk8  = (lane >> 4) << 3;
    int j4   = (lane >> 4) << 2;
    int lbase = wv << 6;

    const f32x4 fz = {0.f, 0.f, 0.f, 0.f};
    const float* xp = (pass ? x2 : x1) + ((long)b << 16);
    const float* vp = V + (pass ? ND : 0);
    f32x4 acc[4][2];
#pragma unroll
    for (int i = 0; i < 4; ++i) { acc[i][0] = fz; acc[i][1] = fz; }
#pragma unroll
    for (int dt = 0; dt < 8; ++dt) {
        int d = (dt << 5) + lk8;
        bf16x8 af[4], bf[2];
#pragma unroll
        for (int lt = 0; lt < 4; ++lt) {
            const float4* s = (const float4*)(xp + ((long)((lbase + (lt << 4) + lrow)) << 8) + d);
            af[lt] = pack8(s[0], s[1]);
        }
#pragma unroll
        for (int nt = 0; nt < 2; ++nt) {
            const float4* s = (const float4*)(vp + (long)((nt << 4) + lrow) * (2 * ND) + d);
            bf[nt] = pack8(s[0], s[1]);
        }
#pragma unroll
        for (int nt = 0; nt < 2; ++nt)
#pragma unroll
            for (int lt = 0; lt < 4; ++lt)
                acc[lt][nt] = __builtin_amdgcn_mfma_f32_16x16x32_bf16(af[lt], bf[nt], acc[lt][nt], 0, 0, 0);
    }
    float* dst = (pass ? lin2 : lin1) + ((long)b << 13);
#pragma unroll
    for (int nt = 0; nt < 2; ++nt) {
        int kk = (nt << 4) + lrow;
        float add = pass ? 0.f : bb[kk];
#pragma unroll
        for (int lt = 0; lt < 4; ++lt) {
            float4 v;
            v.x = acc[lt][nt][0] + add; v.y = acc[lt][nt][1] + add;
            v.z = acc[lt][nt][2] + add; v.w = acc[lt][nt][3] + add;
            *(float4*)(dst + ((long)kk << 8) + lbase + (lt << 4) + j4) = v;
        }
    }
}

// ---------------- main fused kernel ----------------
// grid: 1024 blocks = (k, b, mq), SUPERTILED: 64-block supertiles of 8k x 4b x 2mq,
//       one supertile per XCD at a time (XCD capacity = 32 CU x 2 blocks = 64).
//       Working set per supertile: 8 W-slabs (1 MB) + 4 x1 (0.5 MB) + 4 x2 (0.5 MB) = 2 MB < 4 MB L2.
// 512 threads = 8 waves (4 wave-rows x 2 wave-cols)
// phase A: U^T[m'][d] = sum_e W[k][d][e]*x2[b][m][e], frag loads coalesced -> LDS (64 KiB)
// phase B: O[l][m'] = sum_d x1[b][l][d] * U^T[m'][d], A from global, B from LDS
// ONE barrier per block; 2 blocks/CU, 16 waves/CU.
__launch_bounds__(512, 4)
__global__ void ntn_main(const u16* __restrict__ x1f, const u16* __restrict__ x2f,
                         const u16* __restrict__ Wf,
                         const float* __restrict__ lin1, const float* __restrict__ lin2,
                         float* __restrict__ out) {
    __shared__ u16 ldsU[128 * 256];   // 64 KiB: U^T[m'][d], rows 512 B, swizzle byte^=((m&7)<<4)

    // supertile decode: xcd = bid&7, chunk j = bid>>3 (128 per XCD), 2 supertiles per XCD
    int bid = blockIdx.x;
    int xcd   = bid & 7;
    int j     = bid >> 3;
    int slot  = j >> 6;            // which supertile on this XCD (0/1)
    int inner = j & 63;            // block within supertile
    int st    = (slot << 3) | xcd; // global supertile id 0..15
    int kg = st >> 2, bg = st & 3; // 4 k-groups x 4 b-groups
    int k  = (kg << 3) | (inner >> 3);        // 8 k per supertile
    int b  = (bg << 2) | ((inner >> 1) & 3);  // 4 b per supertile
    int mq = inner & 1;

    int tid  = threadIdx.x;
    int lane = tid & 63;
    int wid  = tid >> 6;
    int wr = wid >> 1;             // wave row 0..3
    int wc = wid & 1;              // wave col 0..1
    int lrow = lane & 15;
    int lk8  = (lane >> 4) << 3;
    int j4   = (lane >> 4) << 2;

    f32x4 acc[4][4];
    const f32x4 fz = {0.f, 0.f, 0.f, 0.f};
#pragma unroll
    for (int i = 0; i < 4; ++i)
#pragma unroll
        for (int jj = 0; jj < 4; ++jj) acc[i][jj] = fz;

    // ================= phase A: U^T = (W[k] @ x2[b]^T)^T, frag loads coalesced ========
    {
        const u16* wp  = Wf  + ((long)k << 16);                      // 16 d-tiles x 8 e-tiles
        const u16* x2p = x2f + ((long)b << 16) + ((long)mq << 15);   // 8 m-tiles x 8 e-tiles
#pragma unroll
        for (int et = 0; et < 8; ++et) {
            bf16x8 af[4], bfr[4];
#pragma unroll
            for (int lt = 0; lt < 4; ++lt)
                af[lt] = *(const bf16x8*)(wp + (((((wr << 2) + lt) << 3) + et) << 9) + (lane << 3));
#pragma unroll
            for (int nt = 0; nt < 4; ++nt)
                bfr[nt] = *(const bf16x8*)(x2p + (((((wc << 2) + nt) << 3) + et) << 9) + (lane << 3));
#pragma unroll
            for (int nt = 0; nt < 4; ++nt)
#pragma unroll
                for (int lt = 0; lt < 4; ++lt)
                    acc[lt][nt] = __builtin_amdgcn_mfma_f32_16x16x32_bf16(af[lt], bfr[nt], acc[lt][nt], 0, 0, 0);
        }
    }

    // ---- write U^T[m'][d] to LDS, swizzled, 4 bf16 packed per 8B write
#pragma unroll
    for (int lt = 0; lt < 4; ++lt) {
        int d0 = (wr << 6) + (lt << 4) + j4;   // consecutive j = consecutive d
#pragma unroll
        for (int nt = 0; nt < 4; ++nt) {
            int m = (wc << 6) + (nt << 4) + lrow;   // local m' 0..127
            ushort4 pk;
            pk.x = f2bf(acc[lt][nt][0]);
            pk.y = f2bf(acc[lt][nt][1]);
            pk.z = f2bf(acc[lt][nt][2]);
            pk.w = f2bf(acc[lt][nt][3]);
            *(ushort4*)((char*)ldsU + (m << 9) + ((d0 << 1) ^ ((m & 7) << 4))) = pk;
        }
    }
    __syncthreads();

#pragma unroll
    for (int i = 0; i < 4; ++i)
#pragma unroll
        for (int jj = 0; jj < 4; ++jj) acc[i][jj] = fz;

    // ================= phase B: O = x1[b] @ U^T^T  (M=l, N=m', K=d) =================
    {
        const u16* x1p = x1f + ((long)b << 16);
#pragma unroll
        for (int dt = 0; dt < 8; ++dt) {
            int d = (dt << 5) + lk8;
            bf16x8 af[4], bfr[4];
#pragma unroll
            for (int lt = 0; lt < 4; ++lt)
                af[lt] = *(const bf16x8*)(x1p + (((((wr << 2) + lt) << 3) + dt) << 9) + (lane << 3));
#pragma unroll
            for (int nt = 0; nt < 4; ++nt) {
                int m = (wc << 6) + (nt << 4) + lrow;
                bfr[nt] = *(const bf16x8*)((const char*)ldsU + (m << 9) + ((d << 1) ^ ((m & 7) << 4)));
            }
#pragma unroll
            for (int nt = 0; nt < 4; ++nt)
#pragma unroll
                for (int lt = 0; lt < 4; ++lt)
                    acc[lt][nt] = __builtin_amdgcn_mfma_f32_16x16x32_bf16(af[lt], bfr[nt], acc[lt][nt], 0, 0, 0);
        }
    }

    // ================= epilogue: + lin1 + lin2 (+b folded), relu, plain store =========
    // (plain stores: L2 merges the two 64 B halves of each 128 B line -> no amplification)
    {
        const float* l1p = lin1 + (((long)(b * NK + k)) << 8);
        const float* l2p = lin2 + (((long)(b * NK + k)) << 8);
        int cbase = (mq << 7) + (wc << 6);
        float colb[4];
#pragma unroll
        for (int nt = 0; nt < 4; ++nt) colb[nt] = l2p[cbase + (nt << 4) + lrow];
        float* outp = out + (((long)(b * NK + k)) << 16);
#pragma unroll
        for (int lt = 0; lt < 4; ++lt) {
#pragma unroll
            for (int jj = 0; jj < 4; ++jj) {
                int l = (wr << 6) + (lt << 4) + j4 + jj;
                float rb = l1p[l];
#pragma unroll
                for (int nt = 0; nt < 4; ++nt) {
                    float v = acc[lt][nt][jj] + rb + colb[nt];
                    v = v > 0.f ? v : 0.f;
                    outp[((long)l << 8) + cbase + (nt << 4) + lrow] = v;
                }
            }
        }
    }
}

extern "C" void kernel_launch(void* const* d_in, const int* in_sizes, int n_in,
                              void* d_out, int out_size, void* d_ws, size_t ws_size,
                              hipStream_t stream) {
    const float* x1 = (const float*)d_in[0];
    const float* x2 = (const float*)d_in[1];
    const float* W  = (const float*)d_in[2];
    const float* V  = (const float*)d_in[3];
    const float* bb = (const float*)d_in[4];
    float* out = (float*)d_out;

    char* ws = (char*)d_ws;
    u16*   x1f  = (u16*)(ws);                               // 2 MiB
    u16*   x2f  = (u16*)(ws + (2l << 20));                  // 2 MiB
    u16*   Wf   = (u16*)(ws + (4l << 20));                  // 4 MiB
    float* lin1 = (float*)(ws + (8l << 20));                // 512 KiB
    float* lin2 = (float*)(ws + (8l << 20) + (512l << 10)); // 512 KiB

    hipLaunchKernelGGL(prep_kernel, dim3(4128), dim3(256), 0, stream,
                       x1, x2, W, V, bb, x1f, x2f, Wf, lin1, lin2);
    hipLaunchKernelGGL(ntn_main, dim3(1024), dim3(512), 0, stream,
                       x1f, x2f, Wf, lin1, lin2, out);
}

// Round 7
// 78.004 us; speedup vs baseline: 2.3988x; 1.4347x over previous
//
#include <hip/hip_runtime.h>
#include <hip/hip_bf16.h>

typedef unsigned short u16;
typedef unsigned short ushort8v __attribute__((ext_vector_type(8)));
typedef __bf16 bf16x8 __attribute__((ext_vector_type(8)));
typedef float f32x4 __attribute__((ext_vector_type(4)));

#define NB 16   // batch
#define NK 32   // K slices
#define ND 256  // D
#define NL 256  // L1 == L2

__device__ __forceinline__ u16 f2bf(float f) {
    __hip_bfloat16 h = __float2bfloat16(f);
    return __builtin_bit_cast(u16, h);
}

__device__ __forceinline__ bf16x8 pack8(float4 a, float4 b) {
    ushort8v u;
    u[0] = f2bf(a.x); u[1] = f2bf(a.y); u[2] = f2bf(a.z); u[3] = f2bf(a.w);
    u[4] = f2bf(b.x); u[5] = f2bf(b.y); u[6] = f2bf(b.z); u[7] = f2bf(b.w);
    return __builtin_bit_cast(bf16x8, u);
}

// Fragment-order layout for a 256x256 matrix X[r][c] (c = contraction dim):
//   buf[((rt*8 + ct)*64 + lane)*8 + (c&7)], rt=r>>4, ct=c>>5,
//   lane = (r&15) | (((c>>3)&3)<<4)
// => a wave's 16x16x32 MFMA fragment is 1 KiB contiguous; coalesced dwordx4 loads.

// ---------------- fused prep ----------------
__global__ void prep_kernel(const float* __restrict__ x1, const float* __restrict__ x2,
                            const float* __restrict__ W, const float* __restrict__ V,
                            const float* __restrict__ bb,
                            u16* __restrict__ x1f, u16* __restrict__ x2f, u16* __restrict__ Wf,
                            float* __restrict__ lin1, float* __restrict__ lin2) {
    int bid = blockIdx.x;
    int tid = threadIdx.x;
    if (bid < 4096) {
        const float* src; u16* dst; long f4;
        if (bid < 1024)      { src = x1; dst = x1f; f4 = (long)bid * 256 + tid; }
        else if (bid < 2048) { src = x2; dst = x2f; f4 = (long)(bid - 1024) * 256 + tid; }
        else                 { src = W;  dst = Wf;  f4 = (long)(bid - 2048) * 256 + tid; }
        long idx = f4 << 2;
        int mat = (int)(idx >> 16);
        int r = (int)((idx >> 8) & 255);
        int c = (int)(idx & 255);
        float4 v = ((const float4*)src)[f4];
        ushort4 o;
        o.x = f2bf(v.x); o.y = f2bf(v.y); o.z = f2bf(v.z); o.w = f2bf(v.w);
        int rt = r >> 4, ct = c >> 5;
        int lane = (r & 15) | (((c >> 3) & 3) << 4);
        long off = ((long)mat << 16) + (((rt << 3) + ct) << 9) + (lane << 3) + (c & 7);
        *(ushort4*)(dst + off) = o;
        return;
    }
    // ---- lin blocks (32): bid2 = (b, pass)
    int bid2 = bid - 4096;
    int b = bid2 >> 1, pass = bid2 & 1;
    int lane = tid & 63;
    int wv   = tid >> 6;
    int lrow = lane & 15;
    int lk8  = (lane >> 4) << 3;
    int j4   = (lane >> 4) << 2;
    int lbase = wv << 6;

    const f32x4 fz = {0.f, 0.f, 0.f, 0.f};
    const float* xp = (pass ? x2 : x1) + ((long)b << 16);
    const float* vp = V + (pass ? ND : 0);
    f32x4 acc[4][2];
#pragma unroll
    for (int i = 0; i < 4; ++i) { acc[i][0] = fz; acc[i][1] = fz; }
#pragma unroll
    for (int dt = 0; dt < 8; ++dt) {
        int d = (dt << 5) + lk8;
        bf16x8 af[4], bf[2];
#pragma unroll
        for (int lt = 0; lt < 4; ++lt) {
            const float4* s = (const float4*)(xp + ((long)((lbase + (lt << 4) + lrow)) << 8) + d);
            af[lt] = pack8(s[0], s[1]);
        }
#pragma unroll
        for (int nt = 0; nt < 2; ++nt) {
            const float4* s = (const float4*)(vp + (long)((nt << 4) + lrow) * (2 * ND) + d);
            bf[nt] = pack8(s[0], s[1]);
        }
#pragma unroll
        for (int nt = 0; nt < 2; ++nt)
#pragma unroll
            for (int lt = 0; lt < 4; ++lt)
                acc[lt][nt] = __builtin_amdgcn_mfma_f32_16x16x32_bf16(af[lt], bf[nt], acc[lt][nt], 0, 0, 0);
    }
    float* dst = (pass ? lin2 : lin1) + ((long)b << 13);
#pragma unroll
    for (int nt = 0; nt < 2; ++nt) {
        int kk = (nt << 4) + lrow;
        float add = pass ? 0.f : bb[kk];
#pragma unroll
        for (int lt = 0; lt < 4; ++lt) {
            float4 v;
            v.x = acc[lt][nt][0] + add; v.y = acc[lt][nt][1] + add;
            v.z = acc[lt][nt][2] + add; v.w = acc[lt][nt][3] + add;
            *(float4*)(dst + ((long)kk << 8) + lbase + (lt << 4) + j4) = v;
        }
    }
}

// ---------------- main fused kernel ----------------
// grid: 1024 blocks = supertiled (k,b,mq); 512 threads = 8 waves.
// phase A: U^T[m'][d] = sum_e W[k][d][e]*x2[b][m][e] -> LDS u16 [128][256] swizzled
//          (wave grid: wrA=d-dim 0..3, wcA=m-dim 0..1)
// phase B: D[m][l] frags: A = U^T (M=m, from LDS), B = x1 (N=l, frag-order global)
//          (wave grid: wrB=m-dim 0..1, wcB=l-dim 0..3)
//          -> lane holds 4 CONSECUTIVE m at fixed l: epilogue packs float4.
// epilogue: two 128-l-row chunks through LDS f32 [128][128] swizzled, then
//           perfectly-coalesced 512B-contiguous nontemporal float4 stores
//           (every 128B line completed by a single instruction).
__launch_bounds__(512, 4)
__global__ void ntn_main(const u16* __restrict__ x1f, const u16* __restrict__ x2f,
                         const u16* __restrict__ Wf,
                         const float* __restrict__ lin1, const float* __restrict__ lin2,
                         float* __restrict__ out) {
    __shared__ __align__(16) char ldsRaw[65536];   // u16[128][256] in A/B; f32[128][128] in epilogue

    // supertile decode: 64-block supertiles of 8k x 4b x 2mq, one per XCD at a time
    int bid = blockIdx.x;
    int xcd   = bid & 7;
    int j     = bid >> 3;
    int slot  = j >> 6;
    int inner = j & 63;
    int st    = (slot << 3) | xcd;
    int kg = st >> 2, bg = st & 3;
    int k  = (kg << 3) | (inner >> 3);
    int b  = (bg << 2) | ((inner >> 1) & 3);
    int mq = inner & 1;

    int tid  = threadIdx.x;
    int lane = tid & 63;
    int wid  = tid >> 6;
    int lrow = lane & 15;
    int lk8  = (lane >> 4) << 3;
    int j4   = (lane >> 4) << 2;

    f32x4 acc[4][4];
    const f32x4 fz = {0.f, 0.f, 0.f, 0.f};
#pragma unroll
    for (int i = 0; i < 4; ++i)
#pragma unroll
        for (int jj = 0; jj < 4; ++jj) acc[i][jj] = fz;

    // ================= phase A: U^T = (W[k] @ x2[b]^T)^T =================
    {
        int wrA = wid >> 1;   // d-dim 0..3
        int wcA = wid & 1;    // m-dim 0..1
        const u16* wp  = Wf  + ((long)k << 16);
        const u16* x2p = x2f + ((long)b << 16) + ((long)mq << 15);
#pragma unroll
        for (int et = 0; et < 8; ++et) {
            bf16x8 af[4], bfr[4];
#pragma unroll
            for (int lt = 0; lt < 4; ++lt)
                af[lt] = *(const bf16x8*)(wp + (((((wrA << 2) + lt) << 3) + et) << 9) + (lane << 3));
#pragma unroll
            for (int nt = 0; nt < 4; ++nt)
                bfr[nt] = *(const bf16x8*)(x2p + (((((wcA << 2) + nt) << 3) + et) << 9) + (lane << 3));
#pragma unroll
            for (int nt = 0; nt < 4; ++nt)
#pragma unroll
                for (int lt = 0; lt < 4; ++lt)
                    acc[lt][nt] = __builtin_amdgcn_mfma_f32_16x16x32_bf16(af[lt], bfr[nt], acc[lt][nt], 0, 0, 0);
        }

        // write U^T[m][d] u16 LDS, swizzle byte^=((m&7)<<4)
#pragma unroll
        for (int lt = 0; lt < 4; ++lt) {
            int d0 = (wrA << 6) + (lt << 4) + j4;
#pragma unroll
            for (int nt = 0; nt < 4; ++nt) {
                int m = (wcA << 6) + (nt << 4) + lrow;
                ushort4 pk;
                pk.x = f2bf(acc[lt][nt][0]);
                pk.y = f2bf(acc[lt][nt][1]);
                pk.z = f2bf(acc[lt][nt][2]);
                pk.w = f2bf(acc[lt][nt][3]);
                *(ushort4*)(ldsRaw + (m << 9) + ((d0 << 1) ^ ((m & 7) << 4))) = pk;
            }
        }
    }
    __syncthreads();

#pragma unroll
    for (int i = 0; i < 4; ++i)
#pragma unroll
        for (int jj = 0; jj < 4; ++jj) acc[i][jj] = fz;

    // ================= phase B: D[m][l] = U^T[m][:] . x1[l][:] =================
    int wrB = wid >> 2;   // m-dim 0..1
    int wcB = wid & 3;    // l-dim 0..3
    {
        const u16* x1p = x1f + ((long)b << 16);
#pragma unroll
        for (int dt = 0; dt < 8; ++dt) {
            int d = (dt << 5) + lk8;
            bf16x8 am[4], xl[4];
#pragma unroll
            for (int mt = 0; mt < 4; ++mt) {
                int m = (wrB << 6) + (mt << 4) + lrow;
                am[mt] = *(const bf16x8*)(ldsRaw + (m << 9) + ((d << 1) ^ ((m & 7) << 4)));
            }
#pragma unroll
            for (int lt = 0; lt < 4; ++lt)
                xl[lt] = *(const bf16x8*)(x1p + (((((wcB << 2) + lt) << 3) + dt) << 9) + (lane << 3));
#pragma unroll
            for (int lt = 0; lt < 4; ++lt)
#pragma unroll
                for (int mt = 0; mt < 4; ++mt)
                    acc[mt][lt] = __builtin_amdgcn_mfma_f32_16x16x32_bf16(am[mt], xl[lt], acc[mt][lt], 0, 0, 0);
        }
    }
    __syncthreads();   // all ldsU reads done; safe to overwrite as f32 chunk

    // ================= epilogue: +lin1+lin2, relu, LDS transpose, coalesced stores ====
    {
        const float* l1p = lin1 + (((long)(b * NK + k)) << 8);
        const float* l2p = lin2 + (((long)(b * NK + k)) << 8) + (mq << 7);
        float* outp = out + (((long)(b * NK + k)) << 16) + (mq << 7);

#pragma unroll
        for (int c = 0; c < 2; ++c) {
            if ((wcB >> 1) == c) {
                // this wave's l rows live in chunk c; write f32 [row 0..127][m 0..127]
                float rb[4];
#pragma unroll
                for (int lt = 0; lt < 4; ++lt)
                    rb[lt] = l1p[(wcB << 6) + (lt << 4) + lrow];
#pragma unroll
                for (int mt = 0; mt < 4; ++mt) {
                    int mloc = (wrB << 6) + (mt << 4) + j4;
                    float4 l2v = *(const float4*)(l2p + mloc);
#pragma unroll
                    for (int lt = 0; lt < 4; ++lt) {
                        int row = ((wcB & 1) << 6) + (lt << 4) + lrow;   // chunk-local l
                        f32x4 v;
                        v[0] = acc[mt][lt][0] + rb[lt] + l2v.x;
                        v[1] = acc[mt][lt][1] + rb[lt] + l2v.y;
                        v[2] = acc[mt][lt][2] + rb[lt] + l2v.z;
                        v[3] = acc[mt][lt][3] + rb[lt] + l2v.w;
                        v[0] = v[0] > 0.f ? v[0] : 0.f;
                        v[1] = v[1] > 0.f ? v[1] : 0.f;
                        v[2] = v[2] > 0.f ? v[2] : 0.f;
                        v[3] = v[3] > 0.f ? v[3] : 0.f;
                        *(f32x4*)(ldsRaw + (row << 9) + ((mloc << 2) ^ ((row & 7) << 4))) = v;
                    }
                }
            }
            __syncthreads();
            // stream chunk: 512 threads x float4 x 8 iters = 64 KiB
#pragma unroll
            for (int it = 0; it < 8; ++it) {
                int g = (it << 9) + tid;
                int row = g >> 5;       // 0..127
                int c4  = g & 31;       // 16B block within 512B row
                f32x4 v = *(const f32x4*)(ldsRaw + (row << 9) + ((c4 << 4) ^ ((row & 7) << 4)));
                __builtin_nontemporal_store(v, (f32x4*)(outp + ((long)((c << 7) + row) << 8) + (c4 << 2)));
            }
            if (c == 0) __syncthreads();
        }
    }
}

extern "C" void kernel_launch(void* const* d_in, const int* in_sizes, int n_in,
                              void* d_out, int out_size, void* d_ws, size_t ws_size,
                              hipStream_t stream) {
    const float* x1 = (const float*)d_in[0];
    const float* x2 = (const float*)d_in[1];
    const float* W  = (const float*)d_in[2];
    const float* V  = (const float*)d_in[3];
    const float* bb = (const float*)d_in[4];
    float* out = (float*)d_out;

    char* ws = (char*)d_ws;
    u16*   x1f  = (u16*)(ws);                               // 2 MiB
    u16*   x2f  = (u16*)(ws + (2l << 20));                  // 2 MiB
    u16*   Wf   = (u16*)(ws + (4l << 20));                  // 4 MiB
    float* lin1 = (float*)(ws + (8l << 20));                // 512 KiB
    float* lin2 = (float*)(ws + (8l << 20) + (512l << 10)); // 512 KiB

    hipLaunchKernelGGL(prep_kernel, dim3(4128), dim3(256), 0, stream,
                       x1, x2, W, V, bb, x1f, x2f, Wf, lin1, lin2);
    hipLaunchKernelGGL(ntn_main, dim3(1024), dim3(512), 0, stream,
                       x1f, x2f, Wf, lin1, lin2, out);
}

// Round 8
// 74.394 us; speedup vs baseline: 2.5152x; 1.0485x over previous
//
#include <hip/hip_runtime.h>
#include <hip/hip_bf16.h>

typedef unsigned short u16;
typedef unsigned short ushort8v __attribute__((ext_vector_type(8)));
typedef __bf16 bf16x8 __attribute__((ext_vector_type(8)));
typedef float f32x4 __attribute__((ext_vector_type(4)));

#define NB 16   // batch
#define NK 32   // K slices
#define ND 256  // D
#define NL 256  // L1 == L2

__device__ __forceinline__ u16 f2bf(float f) {
    __hip_bfloat16 h = __float2bfloat16(f);
    return __builtin_bit_cast(u16, h);
}

__device__ __forceinline__ bf16x8 pack8(float4 a, float4 b) {
    ushort8v u;
    u[0] = f2bf(a.x); u[1] = f2bf(a.y); u[2] = f2bf(a.z); u[3] = f2bf(a.w);
    u[4] = f2bf(b.x); u[5] = f2bf(b.y); u[6] = f2bf(b.z); u[7] = f2bf(b.w);
    return __builtin_bit_cast(bf16x8, u);
}

// async global->LDS, 16B per lane; lds dst = wave-uniform base + lane*16
__device__ __forceinline__ void gload_lds16(const void* g, void* l) {
    __builtin_amdgcn_global_load_lds(
        (const __attribute__((address_space(1))) unsigned int*)g,
        (__attribute__((address_space(3))) unsigned int*)l, 16, 0, 0);
}

// Fragment-order layout for a 256x256 matrix X[r][c] (c = contraction dim):
//   buf[((rt*8 + ct)*64 + lane)*8 + (c&7)], rt=r>>4, ct=c>>5,
//   lane = (r&15) | (((c>>3)&3)<<4)
// => a wave's 16x16x32 MFMA fragment is 1 KiB contiguous; coalesced dwordx4 loads.

// ---------------- fused prep ----------------
__global__ void prep_kernel(const float* __restrict__ x1, const float* __restrict__ x2,
                            const float* __restrict__ W, const float* __restrict__ V,
                            const float* __restrict__ bb,
                            u16* __restrict__ x1f, u16* __restrict__ x2f, u16* __restrict__ Wf,
                            float* __restrict__ lin1, float* __restrict__ lin2) {
    int bid = blockIdx.x;
    int tid = threadIdx.x;
    if (bid < 4096) {
        const float* src; u16* dst; long f4;
        if (bid < 1024)      { src = x1; dst = x1f; f4 = (long)bid * 256 + tid; }
        else if (bid < 2048) { src = x2; dst = x2f; f4 = (long)(bid - 1024) * 256 + tid; }
        else                 { src = W;  dst = Wf;  f4 = (long)(bid - 2048) * 256 + tid; }
        long idx = f4 << 2;
        int mat = (int)(idx >> 16);
        int r = (int)((idx >> 8) & 255);
        int c = (int)(idx & 255);
        float4 v = ((const float4*)src)[f4];
        ushort4 o;
        o.x = f2bf(v.x); o.y = f2bf(v.y); o.z = f2bf(v.z); o.w = f2bf(v.w);
        int rt = r >> 4, ct = c >> 5;
        int lane = (r & 15) | (((c >> 3) & 3) << 4);
        long off = ((long)mat << 16) + (((rt << 3) + ct) << 9) + (lane << 3) + (c & 7);
        *(ushort4*)(dst + off) = o;
        return;
    }
    // ---- lin blocks (32): bid2 = (b, pass)
    int bid2 = bid - 4096;
    int b = bid2 >> 1, pass = bid2 & 1;
    int lane = tid & 63;
    int wv   = tid >> 6;
    int lrow = lane & 15;
    int lk8  = (lane >> 4) << 3;
    int j4   = (lane >> 4) << 2;
    int lbase = wv << 6;

    const f32x4 fz = {0.f, 0.f, 0.f, 0.f};
    const float* xp = (pass ? x2 : x1) + ((long)b << 16);
    const float* vp = V + (pass ? ND : 0);
    f32x4 acc[4][2];
#pragma unroll
    for (int i = 0; i < 4; ++i) { acc[i][0] = fz; acc[i][1] = fz; }
#pragma unroll
    for (int dt = 0; dt < 8; ++dt) {
        int d = (dt << 5) + lk8;
        bf16x8 af[4], bf[2];
#pragma unroll
        for (int lt = 0; lt < 4; ++lt) {
            const float4* s = (const float4*)(xp + ((long)((lbase + (lt << 4) + lrow)) << 8) + d);
            af[lt] = pack8(s[0], s[1]);
        }
#pragma unroll
        for (int nt = 0; nt < 2; ++nt) {
            const float4* s = (const float4*)(vp + (long)((nt << 4) + lrow) * (2 * ND) + d);
            bf[nt] = pack8(s[0], s[1]);
        }
#pragma unroll
        for (int nt = 0; nt < 2; ++nt)
#pragma unroll
            for (int lt = 0; lt < 4; ++lt)
                acc[lt][nt] = __builtin_amdgcn_mfma_f32_16x16x32_bf16(af[lt], bf[nt], acc[lt][nt], 0, 0, 0);
    }
    float* dst = (pass ? lin2 : lin1) + ((long)b << 13);
#pragma unroll
    for (int nt = 0; nt < 2; ++nt) {
        int kk = (nt << 4) + lrow;
        float add = pass ? 0.f : bb[kk];
#pragma unroll
        for (int lt = 0; lt < 4; ++lt) {
            float4 v;
            v.x = acc[lt][nt][0] + add; v.y = acc[lt][nt][1] + add;
            v.z = acc[lt][nt][2] + add; v.w = acc[lt][nt][3] + add;
            *(float4*)(dst + ((long)kk << 8) + lbase + (lt << 4) + j4) = v;
        }
    }
}

// ---------------- main fused kernel ----------------
// grid: 1024 blocks = supertiled (k,b,mq); 512 threads = 8 waves.
// stage:   x2 half-slab (frag-order, 64 KiB LINEAR) -> LDS via global_load_lds w16
// phase A: U^T[m'][d] = sum_e W[k][d][e]*x2[b][m][e]; A-frag W from global (L1-dup x2),
//          B-frag x2 from LDS. acc in regs.
// (barrier) overwrite same LDS with U^T u16 [128][256] swizzled
// phase B: D[m][l]: A = U^T (LDS), B = x1 (frag-order global)
// epilogue: +lin1+lin2, relu; LDS-transpose chunks -> full-line nontemporal stores.
__launch_bounds__(512, 4)
__global__ void ntn_main(const u16* __restrict__ x1f, const u16* __restrict__ x2f,
                         const u16* __restrict__ Wf,
                         const float* __restrict__ lin1, const float* __restrict__ lin2,
                         float* __restrict__ out) {
    __shared__ __align__(16) char ldsRaw[65536];   // x2 stage -> U^T -> epilogue chunks

    // supertile decode: 64-block supertiles of 8k x 4b x 2mq, one per XCD at a time
    int bid = blockIdx.x;
    int xcd   = bid & 7;
    int j     = bid >> 3;
    int slot  = j >> 6;
    int inner = j & 63;
    int st    = (slot << 3) | xcd;
    int kg = st >> 2, bg = st & 3;
    int k  = (kg << 3) | (inner >> 3);
    int b  = (bg << 2) | ((inner >> 1) & 3);
    int mq = inner & 1;

    int tid  = threadIdx.x;
    int lane = tid & 63;
    int wid  = tid >> 6;
    int lrow = lane & 15;
    int j4   = (lane >> 4) << 2;

    // ---- async stage x2 half-slab: 64 chunks of 1 KiB (frag-order is linear)
    {
        const char* src = (const char*)(x2f + ((long)b << 16) + ((long)mq << 15));
#pragma unroll
        for (int it = 0; it < 8; ++it) {
            int chunk = (it << 3) + wid;
            gload_lds16(src + (chunk << 10) + (lane << 4), ldsRaw + (chunk << 10));
        }
    }

    f32x4 acc[4][4];
    const f32x4 fz = {0.f, 0.f, 0.f, 0.f};
#pragma unroll
    for (int i = 0; i < 4; ++i)
#pragma unroll
        for (int jj = 0; jj < 4; ++jj) acc[i][jj] = fz;

    __syncthreads();   // x2 staged

    // ================= phase A: U^T = (W[k] @ x2[b]^T)^T =================
    {
        int wrA = wid >> 1;   // d-dim 0..3
        int wcA = wid & 1;    // m-dim 0..1
        const u16* wp = Wf + ((long)k << 16);
#pragma unroll
        for (int et = 0; et < 8; ++et) {
            bf16x8 af[4], bfr[4];
#pragma unroll
            for (int lt = 0; lt < 4; ++lt)
                af[lt] = *(const bf16x8*)(wp + (((((wrA << 2) + lt) << 3) + et) << 9) + (lane << 3));
#pragma unroll
            for (int nt = 0; nt < 4; ++nt)
                bfr[nt] = *(const bf16x8*)(ldsRaw + ((((((wcA << 2) + nt) << 3) + et) << 10) + (lane << 4)));
#pragma unroll
            for (int nt = 0; nt < 4; ++nt)
#pragma unroll
                for (int lt = 0; lt < 4; ++lt)
                    acc[lt][nt] = __builtin_amdgcn_mfma_f32_16x16x32_bf16(af[lt], bfr[nt], acc[lt][nt], 0, 0, 0);
        }
    }
    __syncthreads();   // all x2 LDS reads done; safe to overwrite with U^T

    // ---- write U^T[m][d] u16 LDS, swizzle byte^=((m&7)<<4)
    {
        int wrA = wid >> 1;
        int wcA = wid & 1;
#pragma unroll
        for (int lt = 0; lt < 4; ++lt) {
            int d0 = (wrA << 6) + (lt << 4) + j4;
#pragma unroll
            for (int nt = 0; nt < 4; ++nt) {
                int m = (wcA << 6) + (nt << 4) + lrow;
                ushort4 pk;
                pk.x = f2bf(acc[lt][nt][0]);
                pk.y = f2bf(acc[lt][nt][1]);
                pk.z = f2bf(acc[lt][nt][2]);
                pk.w = f2bf(acc[lt][nt][3]);
                *(ushort4*)(ldsRaw + (m << 9) + ((d0 << 1) ^ ((m & 7) << 4))) = pk;
            }
        }
    }
    __syncthreads();

#pragma unroll
    for (int i = 0; i < 4; ++i)
#pragma unroll
        for (int jj = 0; jj < 4; ++jj) acc[i][jj] = fz;

    // ================= phase B: D[m][l] = U^T[m][:] . x1[l][:] =================
    int wrB = wid >> 2;   // m-dim 0..1
    int wcB = wid & 3;    // l-dim 0..3
    {
        const u16* x1p = x1f + ((long)b << 16);
        int lk8 = (lane >> 4) << 3;
#pragma unroll
        for (int dt = 0; dt < 8; ++dt) {
            int d = (dt << 5) + lk8;
            bf16x8 am[4], xl[4];
#pragma unroll
            for (int mt = 0; mt < 4; ++mt) {
                int m = (wrB << 6) + (mt << 4) + lrow;
                am[mt] = *(const bf16x8*)(ldsRaw + (m << 9) + ((d << 1) ^ ((m & 7) << 4)));
            }
#pragma unroll
            for (int lt = 0; lt < 4; ++lt)
                xl[lt] = *(const bf16x8*)(x1p + (((((wcB << 2) + lt) << 3) + dt) << 9) + (lane << 3));
#pragma unroll
            for (int lt = 0; lt < 4; ++lt)
#pragma unroll
                for (int mt = 0; mt < 4; ++mt)
                    acc[mt][lt] = __builtin_amdgcn_mfma_f32_16x16x32_bf16(am[mt], xl[lt], acc[mt][lt], 0, 0, 0);
        }
    }
    __syncthreads();   // all U^T reads done; safe to overwrite as f32 chunk

    // ================= epilogue: +lin1+lin2, relu, LDS transpose, coalesced stores ====
    {
        const float* l1p = lin1 + (((long)(b * NK + k)) << 8);
        const float* l2p = lin2 + (((long)(b * NK + k)) << 8) + (mq << 7);
        float* outp = out + (((long)(b * NK + k)) << 16) + (mq << 7);

#pragma unroll
        for (int c = 0; c < 2; ++c) {
            if ((wcB >> 1) == c) {
                float rb[4];
#pragma unroll
                for (int lt = 0; lt < 4; ++lt)
                    rb[lt] = l1p[(wcB << 6) + (lt << 4) + lrow];
#pragma unroll
                for (int mt = 0; mt < 4; ++mt) {
                    int mloc = (wrB << 6) + (mt << 4) + j4;
                    float4 l2v = *(const float4*)(l2p + mloc);
#pragma unroll
                    for (int lt = 0; lt < 4; ++lt) {
                        int row = ((wcB & 1) << 6) + (lt << 4) + lrow;   // chunk-local l
                        f32x4 v;
                        v[0] = acc[mt][lt][0] + rb[lt] + l2v.x;
                        v[1] = acc[mt][lt][1] + rb[lt] + l2v.y;
                        v[2] = acc[mt][lt][2] + rb[lt] + l2v.z;
                        v[3] = acc[mt][lt][3] + rb[lt] + l2v.w;
                        v[0] = v[0] > 0.f ? v[0] : 0.f;
                        v[1] = v[1] > 0.f ? v[1] : 0.f;
                        v[2] = v[2] > 0.f ? v[2] : 0.f;
                        v[3] = v[3] > 0.f ? v[3] : 0.f;
                        *(f32x4*)(ldsRaw + (row << 9) + ((mloc << 2) ^ ((row & 7) << 4))) = v;
                    }
                }
            }
            __syncthreads();
#pragma unroll
            for (int it = 0; it < 8; ++it) {
                int g = (it << 9) + tid;
                int row = g >> 5;       // 0..127
                int c4  = g & 31;       // 16B block within 512B row
                f32x4 v = *(const f32x4*)(ldsRaw + (row << 9) + ((c4 << 4) ^ ((row & 7) << 4)));
                __builtin_nontemporal_store(v, (f32x4*)(outp + ((long)((c << 7) + row) << 8) + (c4 << 2)));
            }
            if (c == 0) __syncthreads();
        }
    }
}

extern "C" void kernel_launch(void* const* d_in, const int* in_sizes, int n_in,
                              void* d_out, int out_size, void* d_ws, size_t ws_size,
                              hipStream_t stream) {
    const float* x1 = (const float*)d_in[0];
    const float* x2 = (const float*)d_in[1];
    const float* W  = (const float*)d_in[2];
    const float* V  = (const float*)d_in[3];
    const float* bb = (const float*)d_in[4];
    float* out = (float*)d_out;

    char* ws = (char*)d_ws;
    u16*   x1f  = (u16*)(ws);                               // 2 MiB
    u16*   x2f  = (u16*)(ws + (2l << 20));                  // 2 MiB
    u16*   Wf   = (u16*)(ws + (4l << 20));                  // 4 MiB
    float* lin1 = (float*)(ws + (8l << 20));                // 512 KiB
    float* lin2 = (float*)(ws + (8l << 20) + (512l << 10)); // 512 KiB

    hipLaunchKernelGGL(prep_kernel, dim3(4128), dim3(256), 0, stream,
                       x1, x2, W, V, bb, x1f, x2f, Wf, lin1, lin2);
    hipLaunchKernelGGL(ntn_main, dim3(1024), dim3(512), 0, stream,
                       x1f, x2f, Wf, lin1, lin2, out);
}

// Round 9
// 72.961 us; speedup vs baseline: 2.5646x; 1.0196x over previous
//
#include <hip/hip_runtime.h>
#include <hip/hip_bf16.h>

typedef unsigned short u16;
typedef unsigned short ushort8v __attribute__((ext_vector_type(8)));
typedef __bf16 bf16x8 __attribute__((ext_vector_type(8)));
typedef float f32x4 __attribute__((ext_vector_type(4)));

#define NB 16   // batch
#define NK 32   // K slices
#define ND 256  // D
#define NL 256  // L1 == L2

__device__ __forceinline__ u16 f2bf(float f) {
    __hip_bfloat16 h = __float2bfloat16(f);
    return __builtin_bit_cast(u16, h);
}

__device__ __forceinline__ bf16x8 pack8(float4 a, float4 b) {
    ushort8v u;
    u[0] = f2bf(a.x); u[1] = f2bf(a.y); u[2] = f2bf(a.z); u[3] = f2bf(a.w);
    u[4] = f2bf(b.x); u[5] = f2bf(b.y); u[6] = f2bf(b.z); u[7] = f2bf(b.w);
    return __builtin_bit_cast(bf16x8, u);
}

// async global->LDS, 16B per lane; lds dst = wave-uniform base + lane*16
__device__ __forceinline__ void gload_lds16(const void* g, void* l) {
    __builtin_amdgcn_global_load_lds(
        (const __attribute__((address_space(1))) unsigned int*)g,
        (__attribute__((address_space(3))) unsigned int*)l, 16, 0, 0);
}

// Fragment-order layout for a 256x256 matrix X[r][c] (c = contraction dim):
//   buf[((rt*8 + ct)*64 + lane)*8 + (c&7)], rt=r>>4, ct=c>>5,
//   lane = (r&15) | (((c>>3)&3)<<4)
// => a wave's 16x16x32 MFMA fragment is 1 KiB contiguous; coalesced dwordx4 loads.

// ---------------- fused prep ----------------
__global__ void prep_kernel(const float* __restrict__ x1, const float* __restrict__ x2,
                            const float* __restrict__ W, const float* __restrict__ V,
                            const float* __restrict__ bb,
                            u16* __restrict__ x1f, u16* __restrict__ x2f, u16* __restrict__ Wf,
                            float* __restrict__ lin1, float* __restrict__ lin2) {
    int bid = blockIdx.x;
    int tid = threadIdx.x;
    if (bid < 4096) {
        const float* src; u16* dst; long f4;
        if (bid < 1024)      { src = x1; dst = x1f; f4 = (long)bid * 256 + tid; }
        else if (bid < 2048) { src = x2; dst = x2f; f4 = (long)(bid - 1024) * 256 + tid; }
        else                 { src = W;  dst = Wf;  f4 = (long)(bid - 2048) * 256 + tid; }
        long idx = f4 << 2;
        int mat = (int)(idx >> 16);
        int r = (int)((idx >> 8) & 255);
        int c = (int)(idx & 255);
        float4 v = ((const float4*)src)[f4];
        ushort4 o;
        o.x = f2bf(v.x); o.y = f2bf(v.y); o.z = f2bf(v.z); o.w = f2bf(v.w);
        int rt = r >> 4, ct = c >> 5;
        int lane = (r & 15) | (((c >> 3) & 3) << 4);
        long off = ((long)mat << 16) + (((rt << 3) + ct) << 9) + (lane << 3) + (c & 7);
        *(ushort4*)(dst + off) = o;
        return;
    }
    // ---- lin blocks (32): bid2 = (b, pass)
    int bid2 = bid - 4096;
    int b = bid2 >> 1, pass = bid2 & 1;
    int lane = tid & 63;
    int wv   = tid >> 6;
    int lrow = lane & 15;
    int lk8  = (lane >> 4) << 3;
    int j4   = (lane >> 4) << 2;
    int lbase = wv << 6;

    const f32x4 fz = {0.f, 0.f, 0.f, 0.f};
    const float* xp = (pass ? x2 : x1) + ((long)b << 16);
    const float* vp = V + (pass ? ND : 0);
    f32x4 acc[4][2];
#pragma unroll
    for (int i = 0; i < 4; ++i) { acc[i][0] = fz; acc[i][1] = fz; }
#pragma unroll
    for (int dt = 0; dt < 8; ++dt) {
        int d = (dt << 5) + lk8;
        bf16x8 af[4], bf[2];
#pragma unroll
        for (int lt = 0; lt < 4; ++lt) {
            const float4* s = (const float4*)(xp + ((long)((lbase + (lt << 4) + lrow)) << 8) + d);
            af[lt] = pack8(s[0], s[1]);
        }
#pragma unroll
        for (int nt = 0; nt < 2; ++nt) {
            const float4* s = (const float4*)(vp + (long)((nt << 4) + lrow) * (2 * ND) + d);
            bf[nt] = pack8(s[0], s[1]);
        }
#pragma unroll
        for (int nt = 0; nt < 2; ++nt)
#pragma unroll
            for (int lt = 0; lt < 4; ++lt)
                acc[lt][nt] = __builtin_amdgcn_mfma_f32_16x16x32_bf16(af[lt], bf[nt], acc[lt][nt], 0, 0, 0);
    }
    float* dst = (pass ? lin2 : lin1) + ((long)b << 13);
#pragma unroll
    for (int nt = 0; nt < 2; ++nt) {
        int kk = (nt << 4) + lrow;
        float add = pass ? 0.f : bb[kk];
#pragma unroll
        for (int lt = 0; lt < 4; ++lt) {
            float4 v;
            v.x = acc[lt][nt][0] + add; v.y = acc[lt][nt][1] + add;
            v.z = acc[lt][nt][2] + add; v.w = acc[lt][nt][3] + add;
            *(float4*)(dst + ((long)kk << 8) + lbase + (lt << 4) + j4) = v;
        }
    }
}

// ---------------- main fused kernel ----------------
// grid: 2048 blocks = supertiled (k,b,mq 0..3); 512 threads = 8 waves; 32 KiB LDS
//       -> 3 blocks/CU (launch_bounds 512,6), phases of co-resident blocks overlap.
// stage:   x2 m-quarter (frag-order, 32 KiB LINEAR) -> LDS via global_load_lds w16
// phase A: U^T[m' 64][d 256] = sum_e W[k][d][e]*x2[b][m][e]; W from global, x2 from LDS
// phase B: D[m][l]: A = U^T (LDS swizzled), B = x1 (frag-order global, no dup)
// epilogue: +lin1+lin2, relu; 2 LDS-transpose chunks f32[128 l][64 m] -> full-line
//           nontemporal stores (256 B runs, every 128 B line completed by one instr).
__launch_bounds__(512, 6)
__global__ void ntn_main(const u16* __restrict__ x1f, const u16* __restrict__ x2f,
                         const u16* __restrict__ Wf,
                         const float* __restrict__ lin1, const float* __restrict__ lin2,
                         float* __restrict__ out) {
    __shared__ __align__(16) char ldsRaw[32768];   // x2 stage -> U^T -> epilogue chunks

    // supertile decode: 128-block supertiles of 8k x 4b x 4mq per XCD slot
    int bid = blockIdx.x;
    int xcd   = bid & 7;
    int j     = bid >> 3;
    int slot  = j >> 7;
    int inner = j & 127;
    int st    = (slot << 3) | xcd;     // 0..15
    int kg = st >> 2, bg = st & 3;
    int k  = (kg << 3) | (inner >> 4);
    int b  = (bg << 2) | ((inner >> 2) & 3);
    int mq = inner & 3;

    int tid  = threadIdx.x;
    int lane = tid & 63;
    int wid  = tid >> 6;
    int lrow = lane & 15;
    int j4   = (lane >> 4) << 2;

    // ---- async stage x2 m-quarter: 32 chunks of 1 KiB (frag-order is linear)
    {
        const char* src = (const char*)(x2f + ((long)b << 16) + ((long)mq << 14));
#pragma unroll
        for (int it = 0; it < 4; ++it) {
            int chunk = (it << 3) + wid;
            gload_lds16(src + (chunk << 10) + (lane << 4), ldsRaw + (chunk << 10));
        }
    }

    f32x4 acc[4][2];
    const f32x4 fz = {0.f, 0.f, 0.f, 0.f};
#pragma unroll
    for (int i = 0; i < 4; ++i) { acc[i][0] = fz; acc[i][1] = fz; }

    __syncthreads();   // x2 staged

    // ================= phase A: U^T[m'][d] =================
    {
        int wrA = wid >> 1;   // d-dim 0..3 (4 d-tiles each)
        int wcA = wid & 1;    // m-dim 0..1 (2 m-tiles each)
        const u16* wp = Wf + ((long)k << 16);
#pragma unroll
        for (int et = 0; et < 8; ++et) {
            bf16x8 af[4], bfr[2];
#pragma unroll
            for (int lt = 0; lt < 4; ++lt)
                af[lt] = *(const bf16x8*)(wp + (((((wrA << 2) + lt) << 3) + et) << 9) + (lane << 3));
#pragma unroll
            for (int nt = 0; nt < 2; ++nt)
                bfr[nt] = *(const bf16x8*)(ldsRaw + ((((((wcA << 1) + nt) << 3) + et) << 10) + (lane << 4)));
#pragma unroll
            for (int nt = 0; nt < 2; ++nt)
#pragma unroll
                for (int lt = 0; lt < 4; ++lt)
                    acc[lt][nt] = __builtin_amdgcn_mfma_f32_16x16x32_bf16(af[lt], bfr[nt], acc[lt][nt], 0, 0, 0);
        }
    }
    __syncthreads();   // all x2 LDS reads done; safe to overwrite with U^T

    // ---- write U^T[m' 64][d 256] u16 LDS (rows 512 B), swizzle byte^=((m&7)<<4)
    {
        int wrA = wid >> 1;
        int wcA = wid & 1;
#pragma unroll
        for (int lt = 0; lt < 4; ++lt) {
            int d0 = (wrA << 6) + (lt << 4) + j4;
#pragma unroll
            for (int nt = 0; nt < 2; ++nt) {
                int m = (wcA << 5) + (nt << 4) + lrow;   // 0..63
                ushort4 pk;
                pk.x = f2bf(acc[lt][nt][0]);
                pk.y = f2bf(acc[lt][nt][1]);
                pk.z = f2bf(acc[lt][nt][2]);
                pk.w = f2bf(acc[lt][nt][3]);
                *(ushort4*)(ldsRaw + (m << 9) + ((d0 << 1) ^ ((m & 7) << 4))) = pk;
            }
        }
    }
    __syncthreads();

#pragma unroll
    for (int i = 0; i < 4; ++i) { acc[i][0] = fz; acc[i][1] = fz; }

    // ================= phase B: D[m 64][l 256]; wave wid owns l-tiles 2*wid,2*wid+1 ====
    {
        const u16* x1p = x1f + ((long)b << 16);
        int lk8 = (lane >> 4) << 3;
#pragma unroll
        for (int dt = 0; dt < 8; ++dt) {
            int d = (dt << 5) + lk8;
            bf16x8 am[4], xl[2];
#pragma unroll
            for (int mt = 0; mt < 4; ++mt) {
                int m = (mt << 4) + lrow;
                am[mt] = *(const bf16x8*)(ldsRaw + (m << 9) + ((d << 1) ^ ((m & 7) << 4)));
            }
#pragma unroll
            for (int lt = 0; lt < 2; ++lt)
                xl[lt] = *(const bf16x8*)(x1p + (((((wid << 1) + lt) << 3) + dt) << 9) + (lane << 3));
#pragma unroll
            for (int lt = 0; lt < 2; ++lt)
#pragma unroll
                for (int mt = 0; mt < 4; ++mt)
                    acc[mt][lt] = __builtin_amdgcn_mfma_f32_16x16x32_bf16(am[mt], xl[lt], acc[mt][lt], 0, 0, 0);
        }
    }
    __syncthreads();   // all U^T reads done; safe to overwrite as f32 chunk

    // ================= epilogue: +lin1+lin2, relu, LDS transpose, coalesced stores ====
    // D element (m = mt*16 + j4 + jj, l = wid*32 + lt*16 + lrow) = acc[mt][lt][jj]
    {
        const float* l1p = lin1 + (((long)(b * NK + k)) << 8);
        const float* l2p = lin2 + (((long)(b * NK + k)) << 8) + (mq << 6);
        float* outp = out + (((long)(b * NK + k)) << 16) + (mq << 6);

#pragma unroll
        for (int c = 0; c < 2; ++c) {
            if ((wid >> 2) == c) {
                float rb[2];
#pragma unroll
                for (int lt = 0; lt < 2; ++lt)
                    rb[lt] = l1p[(wid << 5) + (lt << 4) + lrow];
#pragma unroll
                for (int mt = 0; mt < 4; ++mt) {
                    int mcol = (mt << 4) + j4;
                    float4 l2v = *(const float4*)(l2p + mcol);
#pragma unroll
                    for (int lt = 0; lt < 2; ++lt) {
                        int row = ((wid & 3) << 5) + (lt << 4) + lrow;   // chunk-local l 0..127
                        f32x4 v;
                        v[0] = acc[mt][lt][0] + rb[lt] + l2v.x;
                        v[1] = acc[mt][lt][1] + rb[lt] + l2v.y;
                        v[2] = acc[mt][lt][2] + rb[lt] + l2v.z;
                        v[3] = acc[mt][lt][3] + rb[lt] + l2v.w;
                        v[0] = v[0] > 0.f ? v[0] : 0.f;
                        v[1] = v[1] > 0.f ? v[1] : 0.f;
                        v[2] = v[2] > 0.f ? v[2] : 0.f;
                        v[3] = v[3] > 0.f ? v[3] : 0.f;
                        *(f32x4*)(ldsRaw + (row << 8) + ((mcol << 2) ^ ((row & 7) << 4))) = v;
                    }
                }
            }
            __syncthreads();
            // stream chunk: 32 KiB = 512 threads x f32x4 x 4 iters; 256 B runs per row
#pragma unroll
            for (int it = 0; it < 4; ++it) {
                int g = (it << 9) + tid;
                int row = g >> 4;       // 0..127
                int c4  = g & 15;       // 16B block within 256B row
                f32x4 v = *(const f32x4*)(ldsRaw + (row << 8) + ((c4 << 4) ^ ((row & 7) << 4)));
                __builtin_nontemporal_store(v, (f32x4*)(outp + ((long)((c << 7) + row) << 8) + (c4 << 2)));
            }
            if (c == 0) __syncthreads();
        }
    }
}

extern "C" void kernel_launch(void* const* d_in, const int* in_sizes, int n_in,
                              void* d_out, int out_size, void* d_ws, size_t ws_size,
                              hipStream_t stream) {
    const float* x1 = (const float*)d_in[0];
    const float* x2 = (const float*)d_in[1];
    const float* W  = (const float*)d_in[2];
    const float* V  = (const float*)d_in[3];
    const float* bb = (const float*)d_in[4];
    float* out = (float*)d_out;

    char* ws = (char*)d_ws;
    u16*   x1f  = (u16*)(ws);                               // 2 MiB
    u16*   x2f  = (u16*)(ws + (2l << 20));                  // 2 MiB
    u16*   Wf   = (u16*)(ws + (4l << 20));                  // 4 MiB
    float* lin1 = (float*)(ws + (8l << 20));                // 512 KiB
    float* lin2 = (float*)(ws + (8l << 20) + (512l << 10)); // 512 KiB

    hipLaunchKernelGGL(prep_kernel, dim3(4128), dim3(256), 0, stream,
                       x1, x2, W, V, bb, x1f, x2f, Wf, lin1, lin2);
    hipLaunchKernelGGL(ntn_main, dim3(2048), dim3(512), 0, stream,
                       x1f, x2f, Wf, lin1, lin2, out);
}